// Round 1
// baseline (346.543 us; speedup 1.0000x reference)
//
#include <hip/hip_runtime.h>
#include <math.h>

#define RFL(x) __builtin_amdgcn_readfirstlane(x)

static __device__ __forceinline__ float dot4(float4 a, float4 b) {
  return fmaf(a.x, b.x, fmaf(a.y, b.y, fmaf(a.z, b.z, a.w * b.w)));
}
static __device__ __forceinline__ void fma4(float4& o, float p, float4 v) {
  o.x = fmaf(p, v.x, o.x); o.y = fmaf(p, v.y, o.y);
  o.z = fmaf(p, v.z, o.z); o.w = fmaf(p, v.w, o.w);
}
static __device__ __forceinline__ float4 scale4(float4 a, float s) {
  return make_float4(a.x * s, a.y * s, a.z * s, a.w * s);
}
static __device__ __forceinline__ void add4(float4& a, float4 b) {
  a.x += b.x; a.y += b.y; a.z += b.z; a.w += b.w;
}

// B=16, D=64, L=1280, H=8, hd=8, WIN=5, nW=256, DFF=128
// QKV / AO / LOUT / GOUT layout: (B, L, 64) row-major, channel c = h*8+i.

// ---------------- QKV projection (GEMV, scalar-weight) ----------------
__global__ __launch_bounds__(256) void qkv_kernel(
    const float* __restrict__ x, const float* __restrict__ w_in,
    const float* __restrict__ b_in,
    float* __restrict__ Qo, float* __restrict__ Ko, float* __restrict__ Vo) {
  __shared__ float tile[192][65];
  const int b = blockIdx.y;
  const int l0 = blockIdx.x * 64;
  const int t = threadIdx.x;
  const int lane = t & 63;
  const int w = RFL(t >> 6);
  float xr[64];
#pragma unroll
  for (int d = 0; d < 64; ++d)
    xr[d] = x[(b * 64 + d) * 1280 + l0 + lane];   // coalesced (lanes vary l)
  for (int ci = 0; ci < 48; ++ci) {
    const int c = w * 48 + ci;                     // wave-uniform -> s_loads
    float acc = b_in[c];
    const float* wr = w_in + c * 64;
#pragma unroll
    for (int d = 0; d < 64; ++d) acc = fmaf(xr[d], wr[d], acc);
    tile[c][lane] = acc;                           // stride-65, conflict-free
  }
  __syncthreads();
  for (int arr = 0; arr < 3; ++arr) {
    float* __restrict__ dst = arr == 0 ? Qo : (arr == 1 ? Ko : Vo);
    for (int idx = t; idx < 4096; idx += 256) {
      const int l = idx >> 6, c = idx & 63;
      dst[(b * 1280 + l0 + l) * 64 + c] = tile[arr * 64 + c][l];  // coalesced
    }
  }
}

// ---------------- local windowed attention (WIN=5) ----------------
__global__ __launch_bounds__(256) void local_attn_kernel(
    const float* __restrict__ Q, const float* __restrict__ K,
    const float* __restrict__ V, float* __restrict__ ao) {
  const int g = blockIdx.x * 256 + threadIdx.x;    // 0..163839
  const int qi = g % 5;
  const int h = (g / 5) & 7;
  const int wi = (g / 40) & 255;
  const int b = g / 10240;
  const float4* Q4 = (const float4*)Q;
  const float4* K4 = (const float4*)K;
  const float4* V4 = (const float4*)V;
  const float scale = 0.35355339059327373f;        // 1/sqrt(8)
  const int lq = wi * 5 + qi;
  const int qb = (b * 1280 + lq) * 16 + h * 2;
  const float4 q0 = scale4(Q4[qb], scale);
  const float4 q1 = scale4(Q4[qb + 1], scale);
  float p[5];
  float sum = 0.f;
#pragma unroll
  for (int j = 0; j < 5; ++j) {
    const int kb = (b * 1280 + wi * 5 + j) * 16 + h * 2;
    const float s = dot4(q0, K4[kb]) + dot4(q1, K4[kb + 1]);
    p[j] = __expf(s);                              // scores O(1): no max needed
    sum += p[j];
  }
  const float inv = 1.f / sum;
  float4 o0 = make_float4(0, 0, 0, 0), o1 = make_float4(0, 0, 0, 0);
#pragma unroll
  for (int j = 0; j < 5; ++j) {
    const int vb = (b * 1280 + wi * 5 + j) * 16 + h * 2;
    fma4(o0, p[j], V4[vb]);
    fma4(o1, p[j], V4[vb + 1]);
  }
  float4* ao4 = (float4*)ao;
  ao4[qb] = scale4(o0, inv);
  ao4[qb + 1] = scale4(o1, inv);
}

// ---------------- global attention, split-K over 4 chunks ----------------
#define GSPLIT 4
#define JCH 320
__global__ __launch_bounds__(256) void gattn_kernel(
    const float* __restrict__ Q, const float* __restrict__ K,
    const float* __restrict__ V, float* __restrict__ oacc,
    float* __restrict__ osum) {
  __shared__ float4 Kl[JCH * 2], Vl[JCH * 2];
  const int split = blockIdx.x;
  const int bh = blockIdx.y;
  const int b = bh >> 3, h = bh & 7;
  const int t = threadIdx.x;
  const int j0 = split * JCH;
  const float4* K4 = (const float4*)K;
  const float4* V4 = (const float4*)V;
  for (int idx = t; idx < JCH * 2; idx += 256) {
    const int l = idx >> 1, half = idx & 1;
    const int src = (b * 1280 + j0 + l) * 16 + h * 2 + half;
    Kl[idx] = K4[src];
    Vl[idx] = V4[src];
  }
  __syncthreads();
  const float scale = 0.35355339059327373f;
  const float4* Q4 = (const float4*)Q;
  float4 q0[5], q1[5], o0[5], o1[5];
  float sm[5];
#pragma unroll
  for (int qi = 0; qi < 5; ++qi) {
    const int qb = (b * 1280 + t + qi * 256) * 16 + h * 2;
    q0[qi] = scale4(Q4[qb], scale);
    q1[qi] = scale4(Q4[qb + 1], scale);
    o0[qi] = make_float4(0, 0, 0, 0);
    o1[qi] = make_float4(0, 0, 0, 0);
    sm[qi] = 0.f;
  }
#pragma unroll 2
  for (int jl = 0; jl < JCH; ++jl) {
    const float4 k0 = Kl[2 * jl], k1 = Kl[2 * jl + 1];
    const float4 v0 = Vl[2 * jl], v1 = Vl[2 * jl + 1];
#pragma unroll
    for (int qi = 0; qi < 5; ++qi) {
      const float s = dot4(q0[qi], k0) + dot4(q1[qi], k1);
      const float p = __expf(s);
      sm[qi] += p;
      fma4(o0[qi], p, v0);
      fma4(o1[qi], p, v1);
    }
  }
  float4* oa4 = (float4*)oacc;
#pragma unroll
  for (int qi = 0; qi < 5; ++qi) {
    const int base = (split * 128 + bh) * 1280 + t + qi * 256;
    osum[base] = sm[qi];
    oa4[base * 2] = o0[qi];
    oa4[base * 2 + 1] = o1[qi];
  }
}

__global__ __launch_bounds__(256) void gcombine_kernel(
    const float* __restrict__ oacc, const float* __restrict__ osum,
    float* __restrict__ ao) {
  const int g = blockIdx.x * 256 + threadIdx.x;    // (b*8+h)*1280 + l
  const int l = g % 1280;
  const int bh = g / 1280;
  const int b = bh >> 3, h = bh & 7;
  const float4* oa4 = (const float4*)oacc;
  float s = 0.f;
  float4 a0 = make_float4(0, 0, 0, 0), a1 = make_float4(0, 0, 0, 0);
#pragma unroll
  for (int sp = 0; sp < GSPLIT; ++sp) {
    const int base = sp * 163840 + g;
    s += osum[base];
    add4(a0, oa4[base * 2]);
    add4(a1, oa4[base * 2 + 1]);
  }
  const float inv = 1.f / s;
  float4* ao4 = (float4*)ao;
  const int ob = (b * 1280 + l) * 16 + h * 2;
  ao4[ob] = scale4(a0, inv);
  ao4[ob + 1] = scale4(a1, inv);
}

// ---------------- out-proj + residual + LayerNorm ----------------
__global__ __launch_bounds__(256) void proj_ln_kernel(
    const float* __restrict__ ain, const float* __restrict__ w_out,
    const float* __restrict__ b_out, const float* __restrict__ x,
    const float* __restrict__ gamma, const float* __restrict__ beta,
    float* __restrict__ out) {
  __shared__ float aot[64][65];
  __shared__ float po[64][65];
  const int b = blockIdx.y, l0 = blockIdx.x * 64;
  const int t = threadIdx.x;
  for (int idx = t; idx < 4096; idx += 256) {
    const int l = idx >> 6, d = idx & 63;
    aot[l][d] = ain[(b * 1280 + l0 + l) * 64 + d];
  }
  __syncthreads();
  const int lane = t & 63;
  const int w = RFL(t >> 6);
  float xr[64];
#pragma unroll
  for (int d = 0; d < 64; ++d) xr[d] = aot[lane][d];
  for (int ci = 0; ci < 16; ++ci) {
    const int c = w * 16 + ci;                     // wave-uniform -> s_loads
    float acc = b_out[c];
    const float* wr = w_out + c * 64;
#pragma unroll
    for (int d = 0; d < 64; ++d) acc = fmaf(xr[d], wr[d], acc);
    acc += x[(b * 64 + c) * 1280 + l0 + lane];     // residual, coalesced
    po[lane][c] = acc;
  }
  __syncthreads();
  if (t < 64) {
    float mu = 0.f;
#pragma unroll
    for (int d = 0; d < 64; ++d) mu += po[t][d];
    mu *= 0.015625f;
    float var = 0.f;
#pragma unroll
    for (int d = 0; d < 64; ++d) {
      const float cv = po[t][d] - mu;
      var = fmaf(cv, cv, var);
    }
    var *= 0.015625f;
    const float rs = rsqrtf(var + 1e-5f);
#pragma unroll
    for (int d = 0; d < 64; ++d) po[t][d] = (po[t][d] - mu) * rs;
  }
  __syncthreads();
  for (int idx = t; idx < 4096; idx += 256) {
    const int l = idx >> 6, d = idx & 63;
    out[(b * 1280 + l0 + l) * 64 + d] = fmaf(po[l][d], gamma[d], beta[d]);
  }
}

// ---------------- gated fusion + FFN + LN + transpose ----------------
__global__ __launch_bounds__(256) void ffn_kernel(
    const float* __restrict__ lout, const float* __restrict__ gout,
    const float* __restrict__ lw, const float* __restrict__ w1,
    const float* __restrict__ bf1, const float* __restrict__ w2,
    const float* __restrict__ bf2, const float* __restrict__ g3,
    const float* __restrict__ b3, float* __restrict__ out) {
  __shared__ float fused[64][65];
  __shared__ float part[4][64][65];
  const int b = blockIdx.y, l0 = blockIdx.x * 64;
  const int t = threadIdx.x;
  for (int idx = t; idx < 4096; idx += 256) {
    const int l = idx >> 6, d = idx & 63;
    const float a = 1.f / (1.f + __expf(-lw[d]));
    const int r = (b * 1280 + l0 + l) * 64 + d;
    fused[l][d] = a * lout[r] + (1.f - a) * gout[r];
  }
  __syncthreads();
  const int lane = t & 63;
  const int w = RFL(t >> 6);
  float fr[64];
#pragma unroll
  for (int d = 0; d < 64; ++d) fr[d] = fused[lane][d];
  float hreg[32];
#pragma unroll
  for (int fi = 0; fi < 32; ++fi) {
    const int f = w * 32 + fi;
    float acc = bf1[f];
    const float* wr = w1 + f * 64;
#pragma unroll
    for (int d = 0; d < 64; ++d) acc = fmaf(fr[d], wr[d], acc);
    hreg[fi] = fmaxf(acc, 0.f);
  }
  for (int c = 0; c < 64; ++c) {
    float acc = 0.f;
    const float* wr = w2 + c * 128 + w * 32;
#pragma unroll
    for (int fi = 0; fi < 32; ++fi) acc = fmaf(hreg[fi], wr[fi], acc);
    part[w][lane][c] = acc;
  }
  __syncthreads();
  for (int idx = t; idx < 4096; idx += 256) {
    const int l = idx & 63, c = idx >> 6;
    const float v = part[0][l][c] + part[1][l][c] + part[2][l][c] +
                    part[3][l][c] + bf2[c] + fused[l][c];
    part[0][l][c] = v;
  }
  __syncthreads();
  if (t < 64) {
    float mu = 0.f;
#pragma unroll
    for (int d = 0; d < 64; ++d) mu += part[0][t][d];
    mu *= 0.015625f;
    float var = 0.f;
#pragma unroll
    for (int d = 0; d < 64; ++d) {
      const float cv = part[0][t][d] - mu;
      var = fmaf(cv, cv, var);
    }
    var *= 0.015625f;
    const float rs = rsqrtf(var + 1e-5f);
#pragma unroll
    for (int d = 0; d < 64; ++d) part[0][t][d] = (part[0][t][d] - mu) * rs;
  }
  __syncthreads();
  for (int di = 0; di < 16; ++di) {
    const int d = w * 16 + di;                     // wave-uniform
    out[(b * 64 + d) * 1280 + l0 + lane] =         // coalesced transposed store
        fmaf(part[0][lane][d], g3[d], b3[d]);
  }
}

extern "C" void kernel_launch(void* const* d_in, const int* in_sizes, int n_in,
                              void* d_out, int out_size, void* d_ws,
                              size_t ws_size, hipStream_t stream) {
  const float* x      = (const float*)d_in[0];
  const float* lw_in  = (const float*)d_in[1];
  const float* lb_in  = (const float*)d_in[2];
  const float* lw_out = (const float*)d_in[3];
  const float* lb_out = (const float*)d_in[4];
  const float* gw_in  = (const float*)d_in[5];
  const float* gb_in  = (const float*)d_in[6];
  const float* gw_out = (const float*)d_in[7];
  const float* gb_out = (const float*)d_in[8];
  const float* lwt    = (const float*)d_in[9];
  const float* g1 = (const float*)d_in[10]; const float* b1 = (const float*)d_in[11];
  const float* g2 = (const float*)d_in[12]; const float* b2 = (const float*)d_in[13];
  const float* g3 = (const float*)d_in[14]; const float* b3 = (const float*)d_in[15];
  const float* w1 = (const float*)d_in[16]; const float* bf1 = (const float*)d_in[17];
  const float* w2 = (const float*)d_in[18]; const float* bf2 = (const float*)d_in[19];
  float* out = (float*)d_out;
  float* ws = (float*)d_ws;

  float* Q    = ws;                 // 1310720
  float* Kb   = Q + 1310720;
  float* Vb   = Kb + 1310720;
  float* AO   = Vb + 1310720;
  float* LO   = AO + 1310720;
  float* GO   = LO + 1310720;
  float* OSUM = GO + 1310720;       // 4*163840 = 655360
  float* OACC = OSUM + 655360;      // 4*1310720 = 5242880
  // total ws use: 13,762,560 floats = 55 MB

  dim3 blk(256);
  qkv_kernel<<<dim3(20, 16), blk, 0, stream>>>(x, lw_in, lb_in, Q, Kb, Vb);
  local_attn_kernel<<<dim3(640), blk, 0, stream>>>(Q, Kb, Vb, AO);
  proj_ln_kernel<<<dim3(20, 16), blk, 0, stream>>>(AO, lw_out, lb_out, x, g1, b1, LO);
  qkv_kernel<<<dim3(20, 16), blk, 0, stream>>>(x, gw_in, gb_in, Q, Kb, Vb);
  gattn_kernel<<<dim3(GSPLIT, 128), blk, 0, stream>>>(Q, Kb, Vb, OACC, OSUM);
  gcombine_kernel<<<dim3(640), blk, 0, stream>>>(OACC, OSUM, AO);
  proj_ln_kernel<<<dim3(20, 16), blk, 0, stream>>>(AO, gw_out, gb_out, x, g2, b2, GO);
  ffn_kernel<<<dim3(20, 16), blk, 0, stream>>>(LO, GO, lwt, w1, bf1, w2, bf2, g3, b3, out);
}

// Round 2
// 112.462 us; speedup vs baseline: 3.0814x; 3.0814x over previous
//
#include <hip/hip_runtime.h>
#include <math.h>

typedef short bf16x8 __attribute__((ext_vector_type(8)));
typedef float f32x4 __attribute__((ext_vector_type(4)));
typedef unsigned short u16;
typedef unsigned int u32;

#define RFL(x) __builtin_amdgcn_readfirstlane(x)

static __device__ __forceinline__ float bf2f(u16 s) {
  union { u32 u; float f; } c; c.u = ((u32)s) << 16; return c.f;
}
static __device__ __forceinline__ u16 f2bf(float f) {
  union { float f; u32 u; } c; c.f = f;
  u32 u = c.u + 0x7fffu + ((c.u >> 16) & 1u);
  return (u16)(u >> 16);
}
static __device__ __forceinline__ u32 pk2(float lo, float hi) {
  u32 r;
  asm("v_cvt_pk_bf16_f32 %0, %1, %2" : "=v"(r) : "v"(lo), "v"(hi));
  return r;
}
static __device__ __forceinline__ f32x4 MF(bf16x8 a, bf16x8 b, f32x4 c) {
  return __builtin_amdgcn_mfma_f32_16x16x32_bf16(a, b, c, 0, 0, 0);
}

// B=16, D=64, L=1280, H=8, hd=8, WIN=5, DFF=128
// Token-major layouts: XT[20480][64] bf16; QKV[20480][384] bf16
//   cols: [0:64)Qloc [64:128)Kloc [128:192)Vloc [192:256)Qg [256:320)Kg [320:384)Vg
// AOl/AOg: [20480][64] bf16 (ch = h*8+d)
// MFMA 16x16x32 bf16 layouts (HW-verified): A: lane -> m=l&15, k=8*(l>>4)+j
//   B: lane -> k=8*(l>>4)+j, n=l&15 ; C/D: lane,reg r -> row=4*(l>>4)+r, col=l&15

// ============ K0: x -> XT bf16 (transpose) + weights -> bf16 ============
__global__ __launch_bounds__(256) void prep_kernel(
    const float* __restrict__ x,
    const float* __restrict__ lw_in, const float* __restrict__ gw_in,
    const float* __restrict__ lw_out, const float* __restrict__ gw_out,
    const float* __restrict__ w1, const float* __restrict__ w2,
    u16* __restrict__ XT, u16* __restrict__ Wqkv,
    u16* __restrict__ Wlout, u16* __restrict__ Wgout,
    u16* __restrict__ W1b, u16* __restrict__ W2b) {
  const int t = threadIdx.x;
  if (blockIdx.x < 320) {
    __shared__ __align__(16) float xs[64][68];
    const int b = blockIdx.x / 20, l0 = (blockIdx.x % 20) * 64;
    for (int i = t; i < 4096; i += 256) {
      const int d = i >> 6, tok = i & 63;
      xs[tok][d] = x[(b * 64 + d) * 1280 + l0 + tok];
    }
    __syncthreads();
    for (int i = t; i < 512; i += 256) {
      const int tok = i >> 3, c8 = (i & 7) * 8;
      union { bf16x8 v; u32 u[4]; } o;
      const float* src = &xs[tok][c8];
      o.u[0] = pk2(src[0], src[1]); o.u[1] = pk2(src[2], src[3]);
      o.u[2] = pk2(src[4], src[5]); o.u[3] = pk2(src[6], src[7]);
      *(bf16x8*)(XT + (b * 1280 + l0 + tok) * 64 + c8) = o.v;
    }
  } else {
    const int wb = blockIdx.x - 320;
    for (int f = wb * 256 + t; f < 49152; f += 24 * 256) {
      if (f < 12288)      Wqkv[f] = f2bf(lw_in[f]);
      else if (f < 24576) Wqkv[f] = f2bf(gw_in[f - 12288]);
      else if (f < 28672) Wlout[f - 24576] = f2bf(lw_out[f - 24576]);
      else if (f < 32768) Wgout[f - 28672] = f2bf(gw_out[f - 28672]);
      else if (f < 40960) W1b[f - 32768] = f2bf(w1[f - 32768]);
      else                W2b[f - 40960] = f2bf(w2[f - 40960]);
    }
  }
}

// ============ K1: QKV GEMM (local+global fused), M=20480 N=384 K=64 ======
__global__ __launch_bounds__(256) void qkv_gemm(
    const u16* __restrict__ XT, const u16* __restrict__ Wqkv,
    const float* __restrict__ lb_in, const float* __restrict__ gb_in,
    u16* __restrict__ QKV) {
  const int t = threadIdx.x;
  const int lane = t & 63, w = RFL(t >> 6);
  const int lr = lane & 15, lg = lane >> 4;
  const int m0 = blockIdx.x * 64 + (w & 1) * 32;
  const int n0 = blockIdx.y * 96 + (w >> 1) * 48;
  bf16x8 a[2][2], bb[3][2];
#pragma unroll
  for (int mt = 0; mt < 2; ++mt)
#pragma unroll
    for (int ks = 0; ks < 2; ++ks)
      a[mt][ks] = *(const bf16x8*)(XT + (m0 + mt * 16 + lr) * 64 + ks * 32 + lg * 8);
#pragma unroll
  for (int nt = 0; nt < 3; ++nt)
#pragma unroll
    for (int ks = 0; ks < 2; ++ks)
      bb[nt][ks] = *(const bf16x8*)(Wqkv + (n0 + nt * 16 + lr) * 64 + ks * 32 + lg * 8);
  f32x4 acc[2][3];
#pragma unroll
  for (int mt = 0; mt < 2; ++mt)
#pragma unroll
    for (int nt = 0; nt < 3; ++nt) {
      f32x4 z = {0.f, 0.f, 0.f, 0.f};
      acc[mt][nt] = z;
#pragma unroll
      for (int ks = 0; ks < 2; ++ks)
        acc[mt][nt] = MF(a[mt][ks], bb[nt][ks], acc[mt][nt]);
    }
#pragma unroll
  for (int nt = 0; nt < 3; ++nt) {
    const int col = n0 + nt * 16 + lr;
    const float bias = (col < 192) ? lb_in[col] : gb_in[col - 192];
#pragma unroll
    for (int mt = 0; mt < 2; ++mt)
#pragma unroll
      for (int r = 0; r < 4; ++r) {
        const int row = m0 + mt * 16 + 4 * lg + r;
        QKV[row * 384 + col] = f2bf(acc[mt][nt][r] + bias);
      }
  }
}

// ============ K2: local windowed attention (WIN=5) =======================
__global__ __launch_bounds__(256) void latt(const u16* __restrict__ QKV,
                                            u16* __restrict__ AOl) {
  const int g = blockIdx.x * 256 + threadIdx.x;
  const int qi = g % 5, h = (g / 5) & 7, wi = (g / 40) & 255, b = g / 10240;
  const int row = b * 1280 + wi * 5 + qi;
  const float sc = 0.35355339059327373f;
  float q[8];
  {
    bf16x8 qv = *(const bf16x8*)(QKV + row * 384 + h * 8);
#pragma unroll
    for (int d = 0; d < 8; ++d) q[d] = bf2f((u16)qv[d]) * sc;
  }
  float p[5], sum = 0.f;
#pragma unroll
  for (int j = 0; j < 5; ++j) {
    const int krow = b * 1280 + wi * 5 + j;
    bf16x8 kv = *(const bf16x8*)(QKV + krow * 384 + 64 + h * 8);
    float s = 0.f;
#pragma unroll
    for (int d = 0; d < 8; ++d) s = fmaf(q[d], bf2f((u16)kv[d]), s);
    p[j] = __expf(s); sum += p[j];
  }
  const float inv = 1.f / sum;
  float o[8] = {0, 0, 0, 0, 0, 0, 0, 0};
#pragma unroll
  for (int j = 0; j < 5; ++j) {
    const int vrow = b * 1280 + wi * 5 + j;
    bf16x8 vv = *(const bf16x8*)(QKV + vrow * 384 + 128 + h * 8);
#pragma unroll
    for (int d = 0; d < 8; ++d) o[d] = fmaf(p[j], bf2f((u16)vv[d]), o[d]);
  }
  union { bf16x8 v; u32 u[4]; } ov;
  ov.u[0] = pk2(o[0] * inv, o[1] * inv); ov.u[1] = pk2(o[2] * inv, o[3] * inv);
  ov.u[2] = pk2(o[4] * inv, o[5] * inv); ov.u[3] = pk2(o[6] * inv, o[7] * inv);
  *(bf16x8*)(AOl + row * 64 + h * 8) = ov.v;
}

// ============ K3: global attention, MFMA flash ============================
__global__ __launch_bounds__(256) void gatt(const u16* __restrict__ QKV,
                                            u16* __restrict__ AOg) {
  __shared__ __align__(16) u16 Klds[1280 * 8 + 256];  // + 512B zero region
  __shared__ __align__(16) u16 VT[8 * 1288];          // V^T, padded rows
  __shared__ __align__(16) u16 Pb[4 * 16 * 40];       // wave-private P tiles
  const int t = threadIdx.x;
  const int b = blockIdx.y >> 3, h = blockIdx.y & 7;
  for (int l = t; l < 1280; l += 256) {
    const int src = (b * 1280 + l) * 384 + h * 8;
    bf16x8 kv = *(const bf16x8*)(QKV + src + 256);
    bf16x8 vv = *(const bf16x8*)(QKV + src + 320);
    *(bf16x8*)(Klds + l * 8) = kv;
#pragma unroll
    for (int d = 0; d < 8; ++d) VT[d * 1288 + l] = (u16)vv[d];
  }
  if (t < 128) *(u32*)(Klds + 1280 * 8 + t * 2) = 0;
  __syncthreads();
  const int lane = t & 63, w = RFL(t >> 6);
  const int lr = lane & 15, lg = lane >> 4;
  const int kbase = (lane < 16) ? lr * 16 : 1280 * 16;  // bytes
  const int kinc = (lane < 16) ? 512 : 0;
  const char* kptr0 = (const char*)Klds + kbase;
  const char* vbase = (const char*)VT + (lane & 7) * 2576 + lg * 16;
  u16* pw = Pb + w * 640 + lr * 40 + lg * 4;
  const u16* pr = Pb + w * 640 + lr * 40 + lg * 8;
  const float sc = 0.35355339059327373f;
  for (int qt = 0; qt < 5; ++qt) {
    const int q0 = blockIdx.x * 320 + (w * 5 + qt) * 16;
    const int qrow = b * 1280 + q0 + lr;
    const bf16x8 qf = *(const bf16x8*)(QKV + qrow * 384 + 192 + h * 8);
    f32x4 oacc = {0.f, 0.f, 0.f, 0.f};
    float rs = 0.f;
    const char* kp = kptr0;
    const char* vp = vbase;
#pragma unroll 2
    for (int jt = 0; jt < 40; ++jt) {
      bf16x8 kf0 = *(const bf16x8*)kp;
      bf16x8 kf1 = *(const bf16x8*)(kp + 256);
      f32x4 z = {0.f, 0.f, 0.f, 0.f};
      f32x4 s0 = MF(kf0, qf, z);   // S^T[j][q], j = 4*lg + r (tile 0)
      f32x4 s1 = MF(kf1, qf, z);   // tile 1 (j + 16)
      const float p0 = __expf(s0[0] * sc), p1 = __expf(s0[1] * sc);
      const float p2 = __expf(s0[2] * sc), p3 = __expf(s0[3] * sc);
      const float p4 = __expf(s1[0] * sc), p5 = __expf(s1[1] * sc);
      const float p6 = __expf(s1[2] * sc), p7 = __expf(s1[3] * sc);
      rs += (p0 + p1) + (p2 + p3) + (p4 + p5) + (p6 + p7);
      uint2 w01, w23;
      w01.x = pk2(p0, p1); w01.y = pk2(p2, p3);
      w23.x = pk2(p4, p5); w23.y = pk2(p6, p7);
      *(uint2*)pw = w01;
      *(uint2*)(pw + 16) = w23;
      asm volatile("" ::: "memory");   // order P write -> P read (aliasing)
      bf16x8 pb = *(const bf16x8*)pr;  // B: P^T[jloc][q]
      bf16x8 vf = *(const bf16x8*)vp;  // A: V^T[d][j]
      oacc = MF(vf, pb, oacc);         // out^T[d][q] +=
      kp += kinc; vp += 64;
    }
    rs += __shfl_xor(rs, 16);
    rs += __shfl_xor(rs, 32);
    const float inv = 1.f / rs;
    if (lane < 32) {  // lanes 0..31 hold real d = 4*lg + r in [0,8)
      const int base = qrow * 64 + h * 8 + lg * 4;
      *(u32*)(AOg + base) = pk2(oacc[0] * inv, oacc[1] * inv);
      *(u32*)(AOg + base + 2) = pk2(oacc[2] * inv, oacc[3] * inv);
    }
  }
}

// ============ K4: proj+res+LN (x2) + gate + FFN + LN3 + transpose ========
__global__ __launch_bounds__(256) void tail_kernel(
    const u16* __restrict__ AOl, const u16* __restrict__ AOg,
    const u16* __restrict__ Wlout, const u16* __restrict__ Wgout,
    const u16* __restrict__ W1b, const u16* __restrict__ W2b,
    const float* __restrict__ lb_out, const float* __restrict__ gb_out,
    const float* __restrict__ lwt,
    const float* __restrict__ g1, const float* __restrict__ b1,
    const float* __restrict__ g2, const float* __restrict__ b2,
    const float* __restrict__ g3, const float* __restrict__ b3,
    const float* __restrict__ bf1, const float* __restrict__ bf2,
    const float* __restrict__ x, float* __restrict__ out) {
  __shared__ __align__(16) float xso[64][68];   // residual in, out^T at end
  __shared__ __align__(16) u16 Ft[64 * 64];     // fused (XOR-swizzled)
  __shared__ __align__(16) u16 Ht[64 * 128];    // ffn hidden (XOR-swizzled)
  const int t = threadIdx.x;
  const int b = blockIdx.y, l0 = blockIdx.x * 64;
  for (int i = t; i < 4096; i += 256) {
    const int d = i >> 6, tok = i & 63;
    xso[d][tok] = x[(b * 64 + d) * 1280 + l0 + tok];
  }
  __syncthreads();
  const int lane = t & 63, w = RFL(t >> 6);
  const int lr = lane & 15, lg = lane >> 4;
  const int tb = w * 16;
  const int grow = b * 1280 + l0 + tb;

  // ---- local & global out-proj ----
  f32x4 accl[4], accg[4];
#pragma unroll
  for (int nt = 0; nt < 4; ++nt) { f32x4 z = {0,0,0,0}; accl[nt] = z; accg[nt] = z; }
#pragma unroll
  for (int ks = 0; ks < 2; ++ks) {
    bf16x8 al = *(const bf16x8*)(AOl + (grow + lr) * 64 + ks * 32 + lg * 8);
    bf16x8 ag = *(const bf16x8*)(AOg + (grow + lr) * 64 + ks * 32 + lg * 8);
#pragma unroll
    for (int nt = 0; nt < 4; ++nt) {
      bf16x8 bl = *(const bf16x8*)(Wlout + (nt * 16 + lr) * 64 + ks * 32 + lg * 8);
      bf16x8 bg = *(const bf16x8*)(Wgout + (nt * 16 + lr) * 64 + ks * 32 + lg * 8);
      accl[nt] = MF(al, bl, accl[nt]);
      accg[nt] = MF(ag, bg, accg[nt]);
    }
  }
#pragma unroll
  for (int nt = 0; nt < 4; ++nt) {
    const int col = nt * 16 + lr;
    const float bl = lb_out[col], bg = gb_out[col];
    f32x4 xr = *(const f32x4*)&xso[col][tb + lg * 4];
#pragma unroll
    for (int r = 0; r < 4; ++r) {
      accl[nt][r] += bl + xr[r];
      accg[nt][r] += bg + xr[r];
    }
  }
  // ---- LayerNorm across 64 channels (cross-lane, rows = tokens) ----
  auto LN = [&](f32x4* a, const float* gam, const float* bet) {
    float gv[4], bv[4];
#pragma unroll
    for (int nt = 0; nt < 4; ++nt) { gv[nt] = gam[nt * 16 + lr]; bv[nt] = bet[nt * 16 + lr]; }
#pragma unroll
    for (int r = 0; r < 4; ++r) {
      float s = a[0][r] + a[1][r] + a[2][r] + a[3][r];
      s += __shfl_xor(s, 1); s += __shfl_xor(s, 2);
      s += __shfl_xor(s, 4); s += __shfl_xor(s, 8);
      const float mu = s * 0.015625f;
      float q = 0.f;
#pragma unroll
      for (int nt = 0; nt < 4; ++nt) { const float cv = a[nt][r] - mu; q = fmaf(cv, cv, q); }
      q += __shfl_xor(q, 1); q += __shfl_xor(q, 2);
      q += __shfl_xor(q, 4); q += __shfl_xor(q, 8);
      const float rsq = rsqrtf(q * 0.015625f + 1e-5f);
#pragma unroll
      for (int nt = 0; nt < 4; ++nt)
        a[nt][r] = (a[nt][r] - mu) * rsq * gv[nt] + bv[nt];
    }
  };
  LN(accl, g1, b1);
  LN(accg, g2, b2);
  // ---- gated fusion ----
  f32x4 fus[4];
#pragma unroll
  for (int nt = 0; nt < 4; ++nt) {
    const int col = nt * 16 + lr;
    const float al_ = 1.f / (1.f + __expf(-lwt[col]));
#pragma unroll
    for (int r = 0; r < 4; ++r)
      fus[nt][r] = al_ * accl[nt][r] + (1.f - al_) * accg[nt][r];
  }
#pragma unroll
  for (int nt = 0; nt < 4; ++nt)
#pragma unroll
    for (int r = 0; r < 4; ++r) {
      const int ltok = tb + lg * 4 + r;
      const int byteoff = ((ltok * 64 + nt * 16 + lr) * 2) ^ ((ltok & 7) << 4);
      *(u16*)((char*)Ft + byteoff) = f2bf(fus[nt][r]);
    }
  asm volatile("" ::: "memory");
  // ---- FFN1 (64 -> 128) + ReLU ----
  f32x4 hcc[8];
#pragma unroll
  for (int nt = 0; nt < 8; ++nt) { f32x4 z = {0,0,0,0}; hcc[nt] = z; }
#pragma unroll
  for (int ks = 0; ks < 2; ++ks) {
    const int ltokA = tb + lr;
    const int abyte = (ltokA * 128 + ks * 64 + lg * 16) ^ ((ltokA & 7) << 4);
    bf16x8 af = *(const bf16x8*)((char*)Ft + abyte);
#pragma unroll
    for (int nt = 0; nt < 8; ++nt) {
      bf16x8 bw = *(const bf16x8*)(W1b + (nt * 16 + lr) * 64 + ks * 32 + lg * 8);
      hcc[nt] = MF(af, bw, hcc[nt]);
    }
  }
#pragma unroll
  for (int nt = 0; nt < 8; ++nt) {
    const int f = nt * 16 + lr;
    const float bbv = bf1[f];
#pragma unroll
    for (int r = 0; r < 4; ++r) {
      const float v = fmaxf(hcc[nt][r] + bbv, 0.f);
      const int ltok = tb + lg * 4 + r;
      const int byteoff = ((ltok * 256 + f * 2)) ^ ((ltok & 7) << 4);
      *(u16*)((char*)Ht + byteoff) = f2bf(v);
    }
  }
  asm volatile("" ::: "memory");
  // ---- FFN2 (128 -> 64) + residual(fused) + LN3 ----
  f32x4 occ[4];
#pragma unroll
  for (int nt = 0; nt < 4; ++nt) { f32x4 z = {0,0,0,0}; occ[nt] = z; }
#pragma unroll
  for (int ks = 0; ks < 4; ++ks) {
    const int ltokA = tb + lr;
    const int abyte = (ltokA * 256 + ks * 64 + lg * 16) ^ ((ltokA & 7) << 4);
    bf16x8 af = *(const bf16x8*)((char*)Ht + abyte);
#pragma unroll
    for (int nt = 0; nt < 4; ++nt) {
      bf16x8 bw = *(const bf16x8*)(W2b + (nt * 16 + lr) * 128 + ks * 32 + lg * 8);
      occ[nt] = MF(af, bw, occ[nt]);
    }
  }
#pragma unroll
  for (int nt = 0; nt < 4; ++nt) {
    const float bb2 = bf2[nt * 16 + lr];
#pragma unroll
    for (int r = 0; r < 4; ++r) occ[nt][r] += bb2 + fus[nt][r];
  }
  LN(occ, g3, b3);
  // write transposed into xso (disjoint token columns per wave -> safe alias)
#pragma unroll
  for (int nt = 0; nt < 4; ++nt)
#pragma unroll
    for (int r = 0; r < 4; ++r)
      xso[nt * 16 + lr][tb + lg * 4 + r] = occ[nt][r];
  __syncthreads();
  for (int i = t; i < 4096; i += 256) {
    const int d = i >> 6, tok = i & 63;
    out[(b * 64 + d) * 1280 + l0 + tok] = xso[d][tok];
  }
}

extern "C" void kernel_launch(void* const* d_in, const int* in_sizes, int n_in,
                              void* d_out, int out_size, void* d_ws,
                              size_t ws_size, hipStream_t stream) {
  const float* x      = (const float*)d_in[0];
  const float* lw_in  = (const float*)d_in[1];
  const float* lb_in  = (const float*)d_in[2];
  const float* lw_out = (const float*)d_in[3];
  const float* lb_out = (const float*)d_in[4];
  const float* gw_in  = (const float*)d_in[5];
  const float* gb_in  = (const float*)d_in[6];
  const float* gw_out = (const float*)d_in[7];
  const float* gb_out = (const float*)d_in[8];
  const float* lwt    = (const float*)d_in[9];
  const float* g1 = (const float*)d_in[10]; const float* b1 = (const float*)d_in[11];
  const float* g2 = (const float*)d_in[12]; const float* b2 = (const float*)d_in[13];
  const float* g3 = (const float*)d_in[14]; const float* b3 = (const float*)d_in[15];
  const float* w1 = (const float*)d_in[16]; const float* bf1 = (const float*)d_in[17];
  const float* w2 = (const float*)d_in[18]; const float* bf2 = (const float*)d_in[19];
  float* out = (float*)d_out;

  u16* XT    = (u16*)d_ws;            // 1,310,720
  u16* QKV   = XT + 1310720;          // 7,864,320
  u16* AOl   = QKV + 7864320;         // 1,310,720
  u16* AOg   = AOl + 1310720;         // 1,310,720
  u16* Wqkv  = AOg + 1310720;         // 24,576
  u16* Wlout = Wqkv + 24576;          // 4,096
  u16* Wgout = Wlout + 4096;          // 4,096
  u16* W1b   = Wgout + 4096;          // 8,192
  u16* W2b   = W1b + 8192;            // 8,192  (total ~23.7 MB)

  dim3 blk(256);
  prep_kernel<<<dim3(344), blk, 0, stream>>>(x, lw_in, gw_in, lw_out, gw_out,
                                             w1, w2, XT, Wqkv, Wlout, Wgout, W1b, W2b);
  qkv_gemm<<<dim3(320, 4), blk, 0, stream>>>(XT, Wqkv, lb_in, gb_in, QKV);
  latt<<<dim3(640), blk, 0, stream>>>(QKV, AOl);
  gatt<<<dim3(4, 128), blk, 0, stream>>>(QKV, AOg);
  tail_kernel<<<dim3(20, 16), blk, 0, stream>>>(
      AOl, AOg, Wlout, Wgout, W1b, W2b, lb_out, gb_out, lwt,
      g1, b1, g2, b2, g3, b3, bf1, bf2, x, out);
}